// Round 1
// baseline (37.564 us; speedup 1.0000x reference)
//
#include <hip/hip_runtime.h>

// CRF score: out = (sum_m emissions[b,s,tag] + sum_pairs transitions[t0,t1]) / sum(m)
// B=512, S=512, T=128 (S hardcoded from reference setup; T derived from sizes).

__global__ void crf_score_kernel(const float* __restrict__ emissions,
                                 const int* __restrict__ tags,
                                 const int* __restrict__ mask,
                                 const float* __restrict__ transitions,
                                 double* __restrict__ score_ws,
                                 unsigned int* __restrict__ count_ws,
                                 int total, int S, int T) {
    int idx = blockIdx.x * blockDim.x + threadIdx.x;

    float contrib = 0.0f;
    unsigned int cnt = 0;

    if (idx < total) {
        int s = idx % S;
        int m = mask[idx];
        int t = tags[idx];
        if (m != 0) {
            contrib += emissions[(size_t)idx * (size_t)T + (size_t)t];
            cnt = 1;
        }
        if (s < S - 1) {
            int m2 = mask[idx + 1];
            if (m != 0 && m2 != 0) {
                int t2 = tags[idx + 1];
                contrib += transitions[t * T + t2];
            }
        }
    }

    // wave(64) reduction in double
    double val = (double)contrib;
    #pragma unroll
    for (int off = 32; off > 0; off >>= 1) {
        val += __shfl_down(val, off, 64);
        cnt += __shfl_down(cnt, off, 64);
    }

    __shared__ double s_val[4];
    __shared__ unsigned int s_cnt[4];
    int wave = threadIdx.x >> 6;
    int lane = threadIdx.x & 63;
    if (lane == 0) { s_val[wave] = val; s_cnt[wave] = cnt; }
    __syncthreads();

    if (threadIdx.x == 0) {
        double v = s_val[0] + s_val[1] + s_val[2] + s_val[3];
        unsigned int c = s_cnt[0] + s_cnt[1] + s_cnt[2] + s_cnt[3];
        atomicAdd(score_ws, v);
        atomicAdd(count_ws, c);
    }
}

__global__ void crf_final_kernel(const double* __restrict__ score_ws,
                                 const unsigned int* __restrict__ count_ws,
                                 float* __restrict__ out) {
    out[0] = (float)(score_ws[0] / (double)count_ws[0]);
}

extern "C" void kernel_launch(void* const* d_in, const int* in_sizes, int n_in,
                              void* d_out, int out_size, void* d_ws, size_t ws_size,
                              hipStream_t stream) {
    const float* emissions   = (const float*)d_in[0];
    const int*   tags        = (const int*)d_in[1];
    const int*   mask        = (const int*)d_in[2];
    const float* transitions = (const float*)d_in[3];
    float* out = (float*)d_out;

    const int total = in_sizes[1];            // B*S = 262144
    const int T     = in_sizes[0] / total;    // 128
    const int S     = 512;                    // from reference setup (B=512, S=512)

    double*       score_ws = (double*)d_ws;
    unsigned int* count_ws = (unsigned int*)((char*)d_ws + sizeof(double));

    hipMemsetAsync(d_ws, 0, 16, stream);

    const int block = 256;
    const int grid  = (total + block - 1) / block;   // 1024
    crf_score_kernel<<<grid, block, 0, stream>>>(emissions, tags, mask, transitions,
                                                 score_ws, count_ws, total, S, T);
    crf_final_kernel<<<1, 1, 0, stream>>>(score_ws, count_ws, out);
}

// Round 2
// 11.440 us; speedup vs baseline: 3.2835x; 3.2835x over previous
//
#include <hip/hip_runtime.h>

// CRF score: out = (sum_m emissions[b,s,tag] + sum_pairs transitions[t0,t1]) / sum(m)
// B=512, S=512, T=128. total = B*S = 262144 = 1024 blocks * 256 threads exactly.
//
// Two dispatches, no atomics:
//   kernel 1: per-block (double,uint) partial -> d_ws   (1024 partials)
//   kernel 2: one block reduces 1024 partials -> out scalar

#define NBLK 1024

__global__ void crf_partial_kernel(const float* __restrict__ emissions,
                                   const int* __restrict__ tags,
                                   const int* __restrict__ mask,
                                   const float* __restrict__ transitions,
                                   double* __restrict__ part_val,
                                   unsigned int* __restrict__ part_cnt,
                                   int total, int S, int T) {
    int idx = blockIdx.x * blockDim.x + threadIdx.x;

    float contrib = 0.0f;
    unsigned int cnt = 0;

    if (idx < total) {
        int s = idx % S;
        int m = mask[idx];
        int t = tags[idx];
        if (m != 0) {
            contrib += emissions[(size_t)idx * (size_t)T + (size_t)t];
            cnt = 1;
        }
        if (s < S - 1) {
            int m2 = mask[idx + 1];
            if (m != 0 && m2 != 0) {
                int t2 = tags[idx + 1];
                contrib += transitions[t * T + t2];
            }
        }
    }

    // wave(64) reduction in double
    double val = (double)contrib;
    #pragma unroll
    for (int off = 32; off > 0; off >>= 1) {
        val += __shfl_down(val, off, 64);
        cnt += __shfl_down(cnt, off, 64);
    }

    __shared__ double s_val[4];
    __shared__ unsigned int s_cnt[4];
    int wave = threadIdx.x >> 6;
    int lane = threadIdx.x & 63;
    if (lane == 0) { s_val[wave] = val; s_cnt[wave] = cnt; }
    __syncthreads();

    if (threadIdx.x == 0) {
        part_val[blockIdx.x] = s_val[0] + s_val[1] + s_val[2] + s_val[3];
        part_cnt[blockIdx.x] = s_cnt[0] + s_cnt[1] + s_cnt[2] + s_cnt[3];
    }
}

__global__ void crf_final_kernel(const double* __restrict__ part_val,
                                 const unsigned int* __restrict__ part_cnt,
                                 float* __restrict__ out) {
    // one block of 256 threads; each reads 4 partials
    double v = 0.0;
    unsigned int c = 0;
    #pragma unroll
    for (int i = 0; i < NBLK / 256; ++i) {
        int j = threadIdx.x + i * 256;
        v += part_val[j];
        c += part_cnt[j];
    }
    #pragma unroll
    for (int off = 32; off > 0; off >>= 1) {
        v += __shfl_down(v, off, 64);
        c += __shfl_down(c, off, 64);
    }
    __shared__ double s_val[4];
    __shared__ unsigned int s_cnt[4];
    int wave = threadIdx.x >> 6;
    int lane = threadIdx.x & 63;
    if (lane == 0) { s_val[wave] = v; s_cnt[wave] = c; }
    __syncthreads();
    if (threadIdx.x == 0) {
        double vv = s_val[0] + s_val[1] + s_val[2] + s_val[3];
        unsigned int cc = s_cnt[0] + s_cnt[1] + s_cnt[2] + s_cnt[3];
        out[0] = (float)(vv / (double)cc);
    }
}

extern "C" void kernel_launch(void* const* d_in, const int* in_sizes, int n_in,
                              void* d_out, int out_size, void* d_ws, size_t ws_size,
                              hipStream_t stream) {
    const float* emissions   = (const float*)d_in[0];
    const int*   tags        = (const int*)d_in[1];
    const int*   mask        = (const int*)d_in[2];
    const float* transitions = (const float*)d_in[3];
    float* out = (float*)d_out;

    const int total = in_sizes[1];            // B*S = 262144
    const int T     = in_sizes[0] / total;    // 128
    const int S     = 512;                    // from reference setup

    double*       part_val = (double*)d_ws;
    unsigned int* part_cnt = (unsigned int*)((char*)d_ws + NBLK * sizeof(double));

    const int block = 256;
    crf_partial_kernel<<<NBLK, block, 0, stream>>>(emissions, tags, mask, transitions,
                                                   part_val, part_cnt, total, S, T);
    crf_final_kernel<<<1, block, 0, stream>>>(part_val, part_cnt, out);
}

// Round 3
// 11.354 us; speedup vs baseline: 3.3083x; 1.0076x over previous
//
#include <hip/hip_runtime.h>

// CRF score: out = (sum_m emissions[b,s,tag] + sum_pairs transitions[t0,t1]) / sum(m)
// B=512, S=512, T=128 hardcoded (power-of-2 shifts, no div/mod).
// 2 elements per thread, int2 tag/mask loads. 512 blocks x 256 threads.
// Two dispatches, no atomics.

constexpr int S = 512;
constexpr int T = 128;
constexpr int TOTAL = 512 * 512;   // B*S
constexpr int NBLK = TOTAL / (256 * 2);   // 512

__global__ __launch_bounds__(256) void crf_partial_kernel(
        const float* __restrict__ emissions,
        const int* __restrict__ tags,
        const int* __restrict__ mask,
        const float* __restrict__ transitions,
        double* __restrict__ part_val,
        unsigned int* __restrict__ part_cnt) {
    int gid = blockIdx.x * 256 + threadIdx.x;     // 0 .. TOTAL/2-1
    int idx = gid << 1;                           // first of 2 consecutive elements

    int2 tg = ((const int2*)tags)[gid];
    int2 mk = ((const int2*)mask)[gid];

    float contrib = 0.0f;
    unsigned int cnt = 0;

    // emissions gathers (row = idx, col = tag): offset = idx*128 + tag
    if (mk.x) { contrib += emissions[((size_t)idx << 7) + (size_t)tg.x]; ++cnt; }
    if (mk.y) { contrib += emissions[(((size_t)idx + 1) << 7) + (size_t)tg.y]; ++cnt; }

    // in-thread pair (idx, idx+1): idx is even, S even -> same sequence always
    if (mk.x & mk.y) contrib += transitions[(tg.x << 7) + tg.y];

    // cross-thread pair (idx+1, idx+2): valid unless idx+1 is last in sequence
    int s0 = idx & (S - 1);
    if (s0 != S - 2) {
        if (mk.y) {
            int m2 = mask[idx + 2];
            if (m2) contrib += transitions[(tg.y << 7) + tags[idx + 2]];
        }
    }

    // wave(64) reduction
    double val = (double)contrib;
    #pragma unroll
    for (int off = 32; off > 0; off >>= 1) {
        val += __shfl_down(val, off, 64);
        cnt += __shfl_down(cnt, off, 64);
    }

    __shared__ double s_val[4];
    __shared__ unsigned int s_cnt[4];
    int wave = threadIdx.x >> 6;
    int lane = threadIdx.x & 63;
    if (lane == 0) { s_val[wave] = val; s_cnt[wave] = cnt; }
    __syncthreads();

    if (threadIdx.x == 0) {
        part_val[blockIdx.x] = s_val[0] + s_val[1] + s_val[2] + s_val[3];
        part_cnt[blockIdx.x] = s_cnt[0] + s_cnt[1] + s_cnt[2] + s_cnt[3];
    }
}

__global__ __launch_bounds__(256) void crf_final_kernel(
        const double* __restrict__ part_val,
        const unsigned int* __restrict__ part_cnt,
        float* __restrict__ out) {
    double v = 0.0;
    unsigned int c = 0;
    #pragma unroll
    for (int i = 0; i < NBLK / 256; ++i) {
        int j = threadIdx.x + i * 256;
        v += part_val[j];
        c += part_cnt[j];
    }
    #pragma unroll
    for (int off = 32; off > 0; off >>= 1) {
        v += __shfl_down(v, off, 64);
        c += __shfl_down(c, off, 64);
    }
    __shared__ double s_val[4];
    __shared__ unsigned int s_cnt[4];
    int wave = threadIdx.x >> 6;
    int lane = threadIdx.x & 63;
    if (lane == 0) { s_val[wave] = v; s_cnt[wave] = c; }
    __syncthreads();
    if (threadIdx.x == 0) {
        double vv = s_val[0] + s_val[1] + s_val[2] + s_val[3];
        unsigned int cc = s_cnt[0] + s_cnt[1] + s_cnt[2] + s_cnt[3];
        out[0] = (float)(vv / (double)cc);
    }
}

extern "C" void kernel_launch(void* const* d_in, const int* in_sizes, int n_in,
                              void* d_out, int out_size, void* d_ws, size_t ws_size,
                              hipStream_t stream) {
    const float* emissions   = (const float*)d_in[0];
    const int*   tags        = (const int*)d_in[1];
    const int*   mask        = (const int*)d_in[2];
    const float* transitions = (const float*)d_in[3];
    float* out = (float*)d_out;

    double*       part_val = (double*)d_ws;
    unsigned int* part_cnt = (unsigned int*)((char*)d_ws + NBLK * sizeof(double));

    crf_partial_kernel<<<NBLK, 256, 0, stream>>>(emissions, tags, mask, transitions,
                                                 part_val, part_cnt);
    crf_final_kernel<<<1, 256, 0, stream>>>(part_val, part_cnt, out);
}